// Round 7
// baseline (157.633 us; speedup 1.0000x reference)
//
#include <hip/hip_runtime.h>
#include <hip/hip_bf16.h>

// Locally-connected conv, ALL FP32 in/out, bf16 MFMA compute.
//   x:   (32, 16, 64, 64)        float
//   w:   (60, 60, 16, 5, 5, 16)  float   (per-position 400x16, k innermost)
//   out: (32, 16, 60, 60)        float
//
// Round-7: M-split (was K-split). 128-thr blocks, wave wv owns b-tile wv and
// does all 13 K-chunks -> no sRed, no reduce barrier, LDS = 25.6 KB only ->
// 6 blocks/CU (6 staggered W-DMA streams/CU keeps HBM issue continuous).
//  * W staged via __builtin_amdgcn_global_load_lds width=16 (no scratch).
//  * A-fragments (13 x 16B/lane) prefetched to regs before the barrier.
//  * B-frag: 8x ds_read_b32 from raw [m][k] LDS (2-way banks = free) + pack.
//  * Direct packed store of each wave's 16x16 D-tile; transpose_out epilogue.

#define OUT_HW 60
#define IN_HW  64
#define CIN    16
#define COUT   16
#define NPOS   3600              // OUT_HW*OUT_HW
#define BK     512               // NB*COUT
#define XC_ELE (32u * 64u * 64u * 16u)   // 2,097,152 bf16 elements

typedef __attribute__((ext_vector_type(8))) short bf16x8;
typedef __attribute__((ext_vector_type(4))) float f32x4;

static __device__ __forceinline__ unsigned pk2(float a, float b) {
    union { __hip_bfloat162 h; unsigned u; } cv;
    cv.h = __float22bfloat162_rn(make_float2(a, b));
    return cv.u;
}

// async global->LDS, 16B per lane; l must be wave-uniform, g per-lane.
static __device__ __forceinline__ void g2lds16(const float* g, float* l) {
    __builtin_amdgcn_global_load_lds(
        (const __attribute__((address_space(1))) unsigned int*)g,
        (__attribute__((address_space(3))) unsigned int*)l, 16, 0, 0);
}

// ---- prepass: xc[b][h][w][c] bf16 <- x[b][c][h][w] fp32 (proven r5/r6) ----
__global__ __launch_bounds__(256)
void make_xc(const float* __restrict__ x, ushort* __restrict__ xc) {
    const int bh = blockIdx.x;               // b*64 + h
    const int b = bh >> 6, h = bh & 63;
    const int t = threadIdx.x;
    const int cq = t & 3, wc = t >> 2;
    const float* src = x + ((size_t)(b * CIN) * IN_HW + h) * IN_HW + wc;
    float f[4];
#pragma unroll
    for (int e = 0; e < 4; ++e)
        f[e] = src[(size_t)(cq * 4 + e) * (IN_HW * IN_HW)];
    union { ushort4 v; unsigned u[2]; } o;
    o.u[0] = pk2(f[0], f[1]);
    o.u[1] = pk2(f[2], f[3]);
    *(ushort4*)&xc[((size_t)bh * IN_HW + wc) * CIN + cq * 4] = o.v;
}

// ---- main: one block (128 thr = 2 M-split waves) per output position ----
template<int PACKED>
__global__ __launch_bounds__(128, 3)
void lc_pos(const ushort* __restrict__ xc, const float* __restrict__ w,
            float* __restrict__ dst) {
    __shared__ float sWraw[6400] __attribute__((aligned(16)));  // raw [m][k], 25,600 B

    const int bid = blockIdx.x;
    const int pos = (bid & 7) * 450 + (bid >> 3);   // XCD swizzle (bijective)
    const int i = pos / OUT_HW, j = pos - i * OUT_HW;
    const int t = threadIdx.x;
    const int lane = t & 63, wv = t >> 6;           // wv = b-tile (M-split)
    const int l15 = lane & 15, q = lane >> 4;
    const int qh = q >> 1, c0 = (q & 1) << 3;

    // ---- W: async DMA, 25 x (64 lanes x 16B) = 25,600 B, raw load order ----
    const float* wsrc = w + (size_t)pos * 6400 + lane * 4;
    for (int o = wv; o < 25; o += 2)
        g2lds16(wsrc + o * 256, &sWraw[o * 256]);

    // ---- X: prefetch this wave's 13 A-fragments (overlaps the W DMA) ----
    const int base_hw = i * IN_HW + j;
    const size_t bofs = (size_t)(wv * 16 + l15) * (IN_HW * IN_HW * CIN);
    bf16x8 xa[13];
#pragma unroll
    for (int cc = 0; cc < 13; ++cc) {
        const int uvB = cc * 2 + qh;
        const int uvA = (uvB < 25) ? uvB : 24;      // clamped; W=0 there
        const int uA = (uvA * 13) >> 6;             // uv/5 for uv<=24
        const int vA = uvA - 5 * uA;
        xa[cc] = *(const bf16x8*)(xc + bofs
                   + (size_t)(base_hw + uA * IN_HW + vA) * CIN + c0);
    }

    __syncthreads();   // drains DMA + prefetch (vmcnt), then barrier

    // ---- MFMA: k_r=(uv,c), c innermost; this wave does ALL 13 chunks ----
    f32x4 acc = {0.f, 0.f, 0.f, 0.f};
#pragma unroll
    for (int cc = 0; cc < 13; ++cc) {
        const int uvB = cc * 2 + qh;
        const int okB = (uvB < 25);
        float bfv[8];
#pragma unroll
        for (int jj = 0; jj < 8; ++jj)          // m = (c0+jj)*25 + uvB, k = l15
            bfv[jj] = okB ? sWraw[(c0 + jj) * 400 + uvB * 16 + l15] : 0.f;
        union { bf16x8 v; unsigned u[4]; } pb;
#pragma unroll
        for (int jj = 0; jj < 4; ++jj) pb.u[jj] = pk2(bfv[2 * jj], bfv[2 * jj + 1]);
        acc = __builtin_amdgcn_mfma_f32_16x16x32_bf16(xa[cc], pb.v, acc, 0, 0, 0);
    }

    // ---- direct store: wave's 16x16 D-tile; rows b = wv*16 + q*4 + r ----
#pragma unroll
    for (int r = 0; r < 4; ++r) {
        const int o = (wv * 16 + q * 4 + r) * 16 + l15;   // o = b*16 + k
        if (PACKED) dst[(size_t)pos * BK + o] = acc[r];   // ws[oij][bk]
        else        dst[(size_t)o * NPOS + pos] = acc[r]; // scattered fallback
    }
}

// ---- epilogue: ws[oij][bk] -> out[bk][oij] (proven r3..r6) ----
__global__ __launch_bounds__(256)
void transpose_out(const float* __restrict__ src, float* __restrict__ out) {
    __shared__ float tile[64][65];
    const int o0 = blockIdx.x * 64;
    const int k0 = blockIdx.y * 64;
    const int t  = threadIdx.x;
    const int tx = t & 63, ty = t >> 6;
    for (int r = ty; r < 64; r += 4) {
        const int oij = o0 + r;
        if (oij < NPOS) tile[r][tx] = src[(size_t)oij * BK + k0 + tx];
    }
    __syncthreads();
    for (int r = ty; r < 64; r += 4) {
        const int oij = o0 + tx;
        if (oij < NPOS) out[(size_t)(k0 + r) * NPOS + oij] = tile[tx][r];
    }
}

// ---- emergency fallback (ws too small): naive, correct, slow ----
__global__ __launch_bounds__(256)
void lc_naive(const float* __restrict__ x, const float* __restrict__ w,
              float* __restrict__ out) {
    const int gid = blockIdx.x * 256 + threadIdx.x;
    if (gid >= 32 * COUT * NPOS) return;
    const int j = gid % OUT_HW;
    int rest = gid / OUT_HW;
    const int i = rest % OUT_HW; rest /= OUT_HW;
    const int k = rest % COUT;
    const int b = rest / COUT;
    const float* wp = w + (size_t)(i * OUT_HW + j) * 6400 + k;
    float s = 0.f;
    for (int c = 0; c < CIN; ++c)
        for (int u = 0; u < 5; ++u)
            for (int v = 0; v < 5; ++v)
                s += x[((size_t)(b * CIN + c) * IN_HW + i + u) * IN_HW + j + v]
                   * wp[((c * 5 + u) * 5 + v) * COUT];
    out[gid] = s;
}

extern "C" void kernel_launch(void* const* d_in, const int* in_sizes, int n_in,
                              void* d_out, int out_size, void* d_ws, size_t ws_size,
                              hipStream_t stream) {
    const float* x = (const float*)d_in[0];
    const float* w = (const float*)d_in[1];
    float* out = (float*)d_out;

    const size_t xcBytes  = (size_t)XC_ELE * 2;        // 4,194,304
    const size_t outBytes = (size_t)NPOS * BK * 4;     // 7,372,800
    ushort* xc = (ushort*)d_ws;

    if (ws_size >= xcBytes + outBytes) {
        float* wsOut = (float*)((char*)d_ws + xcBytes);
        make_xc<<<32 * IN_HW, 256, 0, stream>>>(x, xc);
        lc_pos<1><<<NPOS, 128, 0, stream>>>(xc, w, wsOut);
        transpose_out<<<dim3((NPOS + 63) / 64, BK / 64), 256, 0, stream>>>(wsOut, out);
    } else if (ws_size >= xcBytes) {
        make_xc<<<32 * IN_HW, 256, 0, stream>>>(x, xc);
        lc_pos<0><<<NPOS, 128, 0, stream>>>(xc, w, out);
    } else {
        lc_naive<<<(32 * COUT * NPOS + 255) / 256, 256, 0, stream>>>(x, w, out);
    }
}